// Round 4
// baseline (370.259 us; speedup 1.0000x reference)
//
#include <hip/hip_runtime.h>
#include <hip/hip_bf16.h>

// dsfa_former: (1) causal full attention + (2) Linformer attention.
// Inputs fp32, outputs fp32 (per reference). Internal compute bf16 MFMA.
// B=4, N=2048, H=8, d=32, kproj=256. Matmuls via mfma_f32_16x16x32_bf16.
//
// Fragment layouts (learn_hip m89/m91/m120):
//   C/D: per-lane row = quad*4 + reg, col = lane&15
//   A:   lane holds A[m = lane&15][k = quad*8 + j], j=0..7
//   B:   lane holds B[k = quad*8 + j][n = lane&15]
//
// Accuracy: scores (exp-amplified) use split-bf16 (hi+lo):
// S ≈ Ah*Bh + Ah*Bl + Al*Bh  -> ~2^-17 relative input error.

typedef __bf16 bf16x8 __attribute__((ext_vector_type(8)));
typedef float f32x4 __attribute__((ext_vector_type(4)));

union BF8 { uint4 u4; ushort us[8]; bf16x8 b; };

constexpr int B_ = 4, N_ = 2048, H_ = 8, D_ = 32, KP_ = 256, BH_ = 32;
constexpr float SCALE = 0.17677669529663687f;  // 1/sqrt(32)

__device__ __forceinline__ ushort f2bf(float f) {
  unsigned u = __builtin_bit_cast(unsigned, f);
  return (ushort)((u + 0x7FFFu + ((u >> 16) & 1u)) >> 16);
}
__device__ __forceinline__ float bf2f(ushort h) {
  return __builtin_bit_cast(float, (unsigned)h << 16);
}
__device__ __forceinline__ ushort f2bf_lo(float f, ushort hi) {
  return f2bf(f - bf2f(hi));
}

__device__ __forceinline__ float rmax16(float v) {
  v = fmaxf(v, __shfl_xor(v, 1)); v = fmaxf(v, __shfl_xor(v, 2));
  v = fmaxf(v, __shfl_xor(v, 4)); v = fmaxf(v, __shfl_xor(v, 8));
  return v;
}
__device__ __forceinline__ float rsum16(float v) {
  v += __shfl_xor(v, 1); v += __shfl_xor(v, 2);
  v += __shfl_xor(v, 4); v += __shfl_xor(v, 8);
  return v;
}

// Load 8 consecutive floats, return hi/lo bf16 fragments.
__device__ __forceinline__ void load8_split(const float* __restrict__ p,
                                            BF8& hi, BF8& lo) {
  float4 a = *reinterpret_cast<const float4*>(p);
  float4 b = *reinterpret_cast<const float4*>(p + 4);
  float x[8] = {a.x, a.y, a.z, a.w, b.x, b.y, b.z, b.w};
#pragma unroll
  for (int i = 0; i < 8; ++i) {
    hi.us[i] = f2bf(x[i]);
    lo.us[i] = f2bf_lo(x[i], hi.us[i]);
  }
}

// ---------------------------------------------------------------------------
// Kernel 1: Kp[bh][kp][e] = sum_n K[b,n,h,e]*E[n,kp]  (stored as bf16 hi+lo)
//           Vpt[bh][e][kp] = sum_n V[b,n,h,e]*F[n,kp] (transposed bf16)
// Grid: (KP/64, BH). Block 256 (4 waves), wave w owns kp rows [w*16, +16).
// ---------------------------------------------------------------------------
__global__ __launch_bounds__(256) void k_linproj(const float* __restrict__ K,
                                                 const float* __restrict__ V,
                                                 const float* __restrict__ E,
                                                 const float* __restrict__ F,
                                                 ushort* __restrict__ KpHi,
                                                 ushort* __restrict__ KpLo,
                                                 ushort* __restrict__ Vpt) {
  __shared__ alignas(16) ushort Et[64][32];   // [kp_local][n_local]
  __shared__ alignas(16) ushort Ft[64][32];
  __shared__ alignas(16) ushort Kt[32][32];   // [e][n_local]
  __shared__ alignas(16) ushort Vts[32][32];
  const int bh = blockIdx.y, b = bh >> 3, h = bh & 7;
  const int kp0b = blockIdx.x * 64;
  const int t = threadIdx.x;
  const int w = t >> 6, lane = t & 63, quad = lane >> 4, l15 = lane & 15;

  f32x4 accK0 = {0.f,0.f,0.f,0.f}, accK1 = {0.f,0.f,0.f,0.f};
  f32x4 accV0 = {0.f,0.f,0.f,0.f}, accV1 = {0.f,0.f,0.f,0.f};

  for (int n0 = 0; n0 < N_; n0 += 32) {
    __syncthreads();
    {  // stage K,V transposed: thread handles 4 floats of one (n,e4) strip
      const int n = t >> 3, e4 = (t & 7) * 4;
      const size_t base = ((size_t)(b * N_ + n0 + n) * H_ + h) * D_ + e4;
      float4 xk = *reinterpret_cast<const float4*>(K + base);
      float4 xv = *reinterpret_cast<const float4*>(V + base);
      Kt[e4 + 0][n] = f2bf(xk.x); Kt[e4 + 1][n] = f2bf(xk.y);
      Kt[e4 + 2][n] = f2bf(xk.z); Kt[e4 + 3][n] = f2bf(xk.w);
      Vts[e4 + 0][n] = f2bf(xv.x); Vts[e4 + 1][n] = f2bf(xv.y);
      Vts[e4 + 2][n] = f2bf(xv.z); Vts[e4 + 3][n] = f2bf(xv.w);
    }
    {  // stage E,F transposed: thread handles 8 floats of one row
      const int n = t >> 3, k8 = (t & 7) * 8;
      const size_t be = (size_t)(n0 + n) * KP_ + kp0b + k8;
      float4 e0 = *reinterpret_cast<const float4*>(E + be);
      float4 e1 = *reinterpret_cast<const float4*>(E + be + 4);
      float4 f0 = *reinterpret_cast<const float4*>(F + be);
      float4 f1 = *reinterpret_cast<const float4*>(F + be + 4);
      float xe[8] = {e0.x,e0.y,e0.z,e0.w,e1.x,e1.y,e1.z,e1.w};
      float xf[8] = {f0.x,f0.y,f0.z,f0.w,f1.x,f1.y,f1.z,f1.w};
#pragma unroll
      for (int i = 0; i < 8; ++i) { Et[k8 + i][n] = f2bf(xe[i]); Ft[k8 + i][n] = f2bf(xf[i]); }
    }
    __syncthreads();

    BF8 aE, aF, b0, b1;
    aE.u4 = *reinterpret_cast<const uint4*>(&Et[w * 16 + l15][quad * 8]);
    aF.u4 = *reinterpret_cast<const uint4*>(&Ft[w * 16 + l15][quad * 8]);
    b0.u4 = *reinterpret_cast<const uint4*>(&Kt[l15][quad * 8]);
    b1.u4 = *reinterpret_cast<const uint4*>(&Kt[16 + l15][quad * 8]);
    accK0 = __builtin_amdgcn_mfma_f32_16x16x32_bf16(aE.b, b0.b, accK0, 0, 0, 0);
    accK1 = __builtin_amdgcn_mfma_f32_16x16x32_bf16(aE.b, b1.b, accK1, 0, 0, 0);
    b0.u4 = *reinterpret_cast<const uint4*>(&Vts[l15][quad * 8]);
    b1.u4 = *reinterpret_cast<const uint4*>(&Vts[16 + l15][quad * 8]);
    accV0 = __builtin_amdgcn_mfma_f32_16x16x32_bf16(aF.b, b0.b, accV0, 0, 0, 0);
    accV1 = __builtin_amdgcn_mfma_f32_16x16x32_bf16(aF.b, b1.b, accV1, 0, 0, 0);
  }

#pragma unroll
  for (int r = 0; r < 4; ++r) {
    const int kp = kp0b + w * 16 + quad * 4 + r;
    const size_t rowb = ((size_t)bh * KP_ + kp) * D_;
    ushort h0 = f2bf(accK0[r]), h1 = f2bf(accK1[r]);
    KpHi[rowb + l15]      = h0;
    KpHi[rowb + 16 + l15] = h1;
    KpLo[rowb + l15]      = f2bf_lo(accK0[r], h0);
    KpLo[rowb + 16 + l15] = f2bf_lo(accK1[r], h1);
    Vpt[((size_t)bh * D_ + l15) * KP_ + kp]      = f2bf(accV0[r]);
    Vpt[((size_t)bh * D_ + 16 + l15) * KP_ + kp] = f2bf(accV1[r]);
  }
}

// ---------------------------------------------------------------------------
// Kernel 2: causal full attention (flash, online softmax).
// Grid (N/64, BH), block 256; wave w owns q rows [bx*64+w*16, +16).
// K/V chunk staged in LDS shared by all waves; split-bf16 QK^T.
// ---------------------------------------------------------------------------
__global__ __launch_bounds__(256) void k_attn_full(const float* __restrict__ Q,
                                                   const float* __restrict__ K,
                                                   const float* __restrict__ V,
                                                   float* __restrict__ out) {
  __shared__ alignas(16) ushort KsH[32][32];   // [key_local][e] hi
  __shared__ alignas(16) ushort KsL[32][32];   // lo
  __shared__ alignas(16) ushort VsT[32][32];   // [e][key_local]
  __shared__ alignas(16) ushort P[4][16][32];  // per-wave P tile
  const int bh = blockIdx.y, b = bh >> 3, h = bh & 7;
  const int t = threadIdx.x;
  const int w = t >> 6, lane = t & 63;
  const int quad = lane >> 4, l15 = lane & 15;
  const int q0b = blockIdx.x * 64;
  const int q0 = q0b + w * 16;
  const int qlim = q0 + 15;

  BF8 aqh, aql;
  load8_split(Q + ((size_t)(b * N_ + q0 + l15) * H_ + h) * D_ + quad * 8, aqh, aql);

  f32x4 O0 = {0.f,0.f,0.f,0.f}, O1 = {0.f,0.f,0.f,0.f};
  float m[4], l[4];
#pragma unroll
  for (int r = 0; r < 4; ++r) { m[r] = -1e30f; l[r] = 0.f; }
  const f32x4 z = {0.f,0.f,0.f,0.f};

  const int cend = q0b + 64;  // uniform across the block
  for (int c0 = 0; c0 < cend; c0 += 32) {
    __syncthreads();  // protect LDS from overwrite while still in use
    {   // cooperative staging: 256 threads, 4 floats each of K and V
      const int row = t >> 3, e4 = (t & 7) * 4;
      const size_t gbase = ((size_t)(b * N_ + c0 + row) * H_ + h) * D_ + e4;
      float4 xk = *reinterpret_cast<const float4*>(K + gbase);
      float4 xv = *reinterpret_cast<const float4*>(V + gbase);
      float kk[4] = {xk.x, xk.y, xk.z, xk.w};
      float vv[4] = {xv.x, xv.y, xv.z, xv.w};
#pragma unroll
      for (int i = 0; i < 4; ++i) {
        ushort hk = f2bf(kk[i]);
        KsH[row][e4 + i] = hk;
        KsL[row][e4 + i] = f2bf_lo(kk[i], hk);
        VsT[e4 + i][row] = f2bf(vv[i]);
      }
    }
    __syncthreads();  // staging visible

    if (c0 <= qlim) {  // wave-uniform: this wave still has live keys here
      BF8 bh0, bl0, bh1, bl1;
      bh0.u4 = *reinterpret_cast<const uint4*>(&KsH[l15][quad * 8]);
      bl0.u4 = *reinterpret_cast<const uint4*>(&KsL[l15][quad * 8]);
      bh1.u4 = *reinterpret_cast<const uint4*>(&KsH[16 + l15][quad * 8]);
      bl1.u4 = *reinterpret_cast<const uint4*>(&KsL[16 + l15][quad * 8]);
      f32x4 s0 = __builtin_amdgcn_mfma_f32_16x16x32_bf16(aqh.b, bh0.b, z, 0, 0, 0);
      s0 = __builtin_amdgcn_mfma_f32_16x16x32_bf16(aqh.b, bl0.b, s0, 0, 0, 0);
      s0 = __builtin_amdgcn_mfma_f32_16x16x32_bf16(aql.b, bh0.b, s0, 0, 0, 0);
      f32x4 s1 = __builtin_amdgcn_mfma_f32_16x16x32_bf16(aqh.b, bh1.b, z, 0, 0, 0);
      s1 = __builtin_amdgcn_mfma_f32_16x16x32_bf16(aqh.b, bl1.b, s1, 0, 0, 0);
      s1 = __builtin_amdgcn_mfma_f32_16x16x32_bf16(aql.b, bh1.b, s1, 0, 0, 0);

#pragma unroll
      for (int r = 0; r < 4; ++r) {
        const int qrow = q0 + quad * 4 + r;
        const bool ok0 = (c0 + l15      <= qrow);
        const bool ok1 = (c0 + 16 + l15 <= qrow);
        const float v0 = s0[r] * SCALE, v1 = s1[r] * SCALE;
        const float x0 = ok0 ? v0 : -1e30f;
        const float x1 = ok1 ? v1 : -1e30f;
        const float cm = rmax16(fmaxf(x0, x1));  // finite: lane0 always valid
        const float mn = fmaxf(m[r], cm);
        const float alpha = __expf(fmaxf(m[r] - mn, -80.f));
        const float e0 = ok0 ? __expf(fmaxf(v0 - mn, -80.f)) : 0.f;
        const float e1 = ok1 ? __expf(fmaxf(v1 - mn, -80.f)) : 0.f;
        l[r] = l[r] * alpha + rsum16(e0 + e1);
        m[r] = mn;
        O0[r] *= alpha; O1[r] *= alpha;
        P[w][quad * 4 + r][l15]      = f2bf(e0);
        P[w][quad * 4 + r][16 + l15] = f2bf(e1);
      }
    }
    __syncthreads();  // P visible (all waves reach this)

    if (c0 <= qlim) {
      BF8 ap, bv0, bv1;
      ap.u4  = *reinterpret_cast<const uint4*>(&P[w][l15][quad * 8]);
      bv0.u4 = *reinterpret_cast<const uint4*>(&VsT[l15][quad * 8]);
      bv1.u4 = *reinterpret_cast<const uint4*>(&VsT[16 + l15][quad * 8]);
      O0 = __builtin_amdgcn_mfma_f32_16x16x32_bf16(ap.b, bv0.b, O0, 0, 0, 0);
      O1 = __builtin_amdgcn_mfma_f32_16x16x32_bf16(ap.b, bv1.b, O1, 0, 0, 0);
    }
  }

#pragma unroll
  for (int r = 0; r < 4; ++r) {
    const float inv = 1.f / l[r];  // l >= exp(-80) > 0 always
    const int qrow = q0 + quad * 4 + r;
    const size_t base = ((size_t)(b * N_ + qrow) * H_ + h) * D_;
    out[base + l15]      = O0[r] * inv;
    out[base + 16 + l15] = O1[r] * inv;
  }
}

// ---------------------------------------------------------------------------
// Kernel 3: Linformer attention: s = Q*Kp^T*scale, softmax over 256, *Vp.
// Grid (N/64, BH), block 256; wave w owns q rows [bx*64+w*16, +16).
// ---------------------------------------------------------------------------
__global__ __launch_bounds__(256) void k_attn_lin(const float* __restrict__ Q,
                                                  const ushort* __restrict__ KpHi,
                                                  const ushort* __restrict__ KpLo,
                                                  const ushort* __restrict__ Vpt,
                                                  float* __restrict__ out) {
  __shared__ alignas(16) ushort P[4][16][KP_];  // 32 KB
  const int bh = blockIdx.y, b = bh >> 3, h = bh & 7;
  const int w = threadIdx.x >> 6, lane = threadIdx.x & 63;
  const int quad = lane >> 4, l15 = lane & 15;
  const int q0 = blockIdx.x * 64 + w * 16;

  BF8 aqh, aql;
  load8_split(Q + ((size_t)(b * N_ + q0 + l15) * H_ + h) * D_ + quad * 8, aqh, aql);

  const f32x4 z = {0.f,0.f,0.f,0.f};
  f32x4 s[16];
#pragma unroll
  for (int kt = 0; kt < 16; ++kt) {
    BF8 bkh, bkl;
    const size_t rb = ((size_t)bh * KP_ + kt * 16 + l15) * D_ + quad * 8;
    bkh.u4 = *reinterpret_cast<const uint4*>(KpHi + rb);
    bkl.u4 = *reinterpret_cast<const uint4*>(KpLo + rb);
    s[kt] = __builtin_amdgcn_mfma_f32_16x16x32_bf16(aqh.b, bkh.b, z, 0, 0, 0);
    s[kt] = __builtin_amdgcn_mfma_f32_16x16x32_bf16(aqh.b, bkl.b, s[kt], 0, 0, 0);
    s[kt] = __builtin_amdgcn_mfma_f32_16x16x32_bf16(aql.b, bkh.b, s[kt], 0, 0, 0);
  }

  float l[4];
#pragma unroll
  for (int r = 0; r < 4; ++r) {
    float mm = -1e30f;
#pragma unroll
    for (int kt = 0; kt < 16; ++kt) mm = fmaxf(mm, s[kt][r]);
    mm = rmax16(mm * SCALE);
    float sum = 0.f;
#pragma unroll
    for (int kt = 0; kt < 16; ++kt) {
      const float e = __expf(fmaxf(s[kt][r] * SCALE - mm, -80.f));
      sum += e;
      P[w][quad * 4 + r][kt * 16 + l15] = f2bf(e);
    }
    l[r] = rsum16(sum);
  }
  __syncthreads();  // P visible (uniform control flow)

  f32x4 O0 = {0.f,0.f,0.f,0.f}, O1 = {0.f,0.f,0.f,0.f};
#pragma unroll
  for (int c = 0; c < 8; ++c) {
    BF8 ap, bv0, bv1;
    ap.u4 = *reinterpret_cast<const uint4*>(&P[w][l15][c * 32 + quad * 8]);
    bv0.u4 = *reinterpret_cast<const uint4*>(
        Vpt + ((size_t)bh * D_ + l15) * KP_ + c * 32 + quad * 8);
    bv1.u4 = *reinterpret_cast<const uint4*>(
        Vpt + ((size_t)bh * D_ + 16 + l15) * KP_ + c * 32 + quad * 8);
    O0 = __builtin_amdgcn_mfma_f32_16x16x32_bf16(ap.b, bv0.b, O0, 0, 0, 0);
    O1 = __builtin_amdgcn_mfma_f32_16x16x32_bf16(ap.b, bv1.b, O1, 0, 0, 0);
  }

#pragma unroll
  for (int r = 0; r < 4; ++r) {
    const float inv = 1.f / l[r];
    const int qrow = q0 + quad * 4 + r;
    const size_t base = ((size_t)(b * N_ + qrow) * H_ + h) * D_;
    out[base + l15]      = O0[r] * inv;
    out[base + 16 + l15] = O1[r] * inv;
  }
}

// ---------------------------------------------------------------------------
extern "C" void kernel_launch(void* const* d_in, const int* in_sizes, int n_in,
                              void* d_out, int out_size, void* d_ws, size_t ws_size,
                              hipStream_t stream) {
  const float* Q = (const float*)d_in[0];
  const float* K = (const float*)d_in[1];
  const float* V = (const float*)d_in[2];
  const float* E = (const float*)d_in[3];
  const float* F = (const float*)d_in[4];
  float* out = (float*)d_out;

  // workspace (bf16 elements): 1.5 MB total
  ushort* KpHi = (ushort*)d_ws;                      // [BH][KP][D] : 512 KB
  ushort* KpLo = KpHi + (size_t)BH_ * KP_ * D_;      // [BH][KP][D] : 512 KB
  ushort* Vpt  = KpLo + (size_t)BH_ * KP_ * D_;      // [BH][D][KP] : 512 KB

  k_linproj<<<dim3(KP_ / 64, BH_), 256, 0, stream>>>(K, V, E, F, KpHi, KpLo, Vpt);
  k_attn_full<<<dim3(N_ / 64, BH_), 256, 0, stream>>>(Q, K, V, out);
  k_attn_lin<<<dim3(N_ / 64, BH_), 256, 0, stream>>>(
      Q, KpHi, KpLo, Vpt, out + (size_t)B_ * N_ * H_ * D_);
}

// Round 5
// 276.177 us; speedup vs baseline: 1.3407x; 1.3407x over previous
//
#include <hip/hip_runtime.h>
#include <hip/hip_bf16.h>

// dsfa_former: (1) causal full attention + (2) Linformer attention.
// Inputs fp32, outputs fp32. Internal compute bf16 MFMA (split-bf16 scores).
// B=4, N=2048, H=8, d=32, kproj=256.
//
// Round-5 structure: one-shot prep kernels build bf16 (and transposed)
// copies of K/V/E/F so every MFMA fragment in the hot kernels is a single
// contiguous uint4 load from global (L2-resident). No __syncthreads in any
// hot loop; the only intra-kernel dependency is the per-wave P tile LDS
// round-trip, fenced with a wave-local s_waitcnt lgkmcnt(0).
//
// Fragment layouts (learn_hip m89/m91/m120):
//   C/D: per-lane row = quad*4 + reg, col = lane&15
//   A:   lane holds A[m = lane&15][k = quad*8 + j], j=0..7
//   B:   lane holds B[k = quad*8 + j][n = lane&15]

typedef __bf16 bf16x8 __attribute__((ext_vector_type(8)));
typedef float f32x4 __attribute__((ext_vector_type(4)));

union BF8 { uint4 u4; ushort us[8]; bf16x8 b; };

constexpr int B_ = 4, N_ = 2048, H_ = 8, D_ = 32, KP_ = 256, BH_ = 32;
constexpr float SCALE = 0.17677669529663687f;  // 1/sqrt(32)

__device__ __forceinline__ ushort f2bf(float f) {
  unsigned u = __builtin_bit_cast(unsigned, f);
  return (ushort)((u + 0x7FFFu + ((u >> 16) & 1u)) >> 16);
}
__device__ __forceinline__ float bf2f(ushort h) {
  return __builtin_bit_cast(float, (unsigned)h << 16);
}
__device__ __forceinline__ ushort f2bf_lo(float f, ushort hi) {
  return f2bf(f - bf2f(hi));
}

__device__ __forceinline__ float rmax16(float v) {
  v = fmaxf(v, __shfl_xor(v, 1)); v = fmaxf(v, __shfl_xor(v, 2));
  v = fmaxf(v, __shfl_xor(v, 4)); v = fmaxf(v, __shfl_xor(v, 8));
  return v;
}
__device__ __forceinline__ float rsum16(float v) {
  v += __shfl_xor(v, 1); v += __shfl_xor(v, 2);
  v += __shfl_xor(v, 4); v += __shfl_xor(v, 8);
  return v;
}

// Wave-local LDS write->read fence: drains this wave's DS ops; the memory
// clobber pins compiler/scheduler ordering. No block barrier.
__device__ __forceinline__ void lds_fence_wave() {
  asm volatile("s_waitcnt lgkmcnt(0)" ::: "memory");
}

// Load 8 consecutive floats, return hi/lo bf16 fragments.
__device__ __forceinline__ void load8_split(const float* __restrict__ p,
                                            BF8& hi, BF8& lo) {
  float4 a = *reinterpret_cast<const float4*>(p);
  float4 b = *reinterpret_cast<const float4*>(p + 4);
  float x[8] = {a.x, a.y, a.z, a.w, b.x, b.y, b.z, b.w};
#pragma unroll
  for (int i = 0; i < 8; ++i) {
    hi.us[i] = f2bf(x[i]);
    lo.us[i] = f2bf_lo(x[i], hi.us[i]);
  }
}

// ---------------------------------------------------------------------------
// Prep 1: K -> KH/KL[bh][n][e] (split bf16, row-major), K -> Kt[bh][e][n],
//         V -> Vt[bh][e][n]. Grid (N/64, BH), block 256. One-shot.
// ---------------------------------------------------------------------------
__global__ __launch_bounds__(256) void k_prep_kv(const float* __restrict__ K,
                                                 const float* __restrict__ V,
                                                 ushort* __restrict__ KH,
                                                 ushort* __restrict__ KL,
                                                 ushort* __restrict__ Kt,
                                                 ushort* __restrict__ Vt) {
  __shared__ alignas(16) ushort Tk[D_][66];  // [e][n_local], padded
  __shared__ alignas(16) ushort Tv[D_][66];
  const int bh = blockIdx.y, b = bh >> 3, h = bh & 7;
  const int n0 = blockIdx.x * 64;
  const int t = threadIdx.x;
  {
    const int row = t >> 2, e8 = (t & 3) * 8;
    const size_t gbase = ((size_t)(b * N_ + n0 + row) * H_ + h) * D_ + e8;
    float4 k0 = *reinterpret_cast<const float4*>(K + gbase);
    float4 k1 = *reinterpret_cast<const float4*>(K + gbase + 4);
    float4 v0 = *reinterpret_cast<const float4*>(V + gbase);
    float4 v1 = *reinterpret_cast<const float4*>(V + gbase + 4);
    float kk[8] = {k0.x,k0.y,k0.z,k0.w,k1.x,k1.y,k1.z,k1.w};
    float vv[8] = {v0.x,v0.y,v0.z,v0.w,v1.x,v1.y,v1.z,v1.w};
    BF8 xh, xl;
#pragma unroll
    for (int i = 0; i < 8; ++i) {
      xh.us[i] = f2bf(kk[i]);
      xl.us[i] = f2bf_lo(kk[i], xh.us[i]);
      Tk[e8 + i][row] = xh.us[i];
      Tv[e8 + i][row] = f2bf(vv[i]);
    }
    const size_t ob = ((size_t)bh * N_ + n0 + row) * D_ + e8;
    *reinterpret_cast<uint4*>(KH + ob) = xh.u4;
    *reinterpret_cast<uint4*>(KL + ob) = xl.u4;
  }
  __syncthreads();
  {
    const int e = t >> 3, n8 = (t & 7) * 8;
    BF8 xk, xv;
#pragma unroll
    for (int i = 0; i < 8; ++i) { xk.us[i] = Tk[e][n8 + i]; xv.us[i] = Tv[e][n8 + i]; }
    const size_t ob = ((size_t)bh * D_ + e) * N_ + n0 + n8;
    *reinterpret_cast<uint4*>(Kt + ob) = xk.u4;
    *reinterpret_cast<uint4*>(Vt + ob) = xv.u4;
  }
}

// ---------------------------------------------------------------------------
// Prep 2: E[N][KP] -> Et[KP][N] bf16 (z=0), F -> Ft (z=1).
// Grid (N/64, KP/64, 2), block 256. One-shot.
// ---------------------------------------------------------------------------
__global__ __launch_bounds__(256) void k_prep_ef(const float* __restrict__ E,
                                                 const float* __restrict__ F,
                                                 ushort* __restrict__ Et,
                                                 ushort* __restrict__ Ft) {
  __shared__ alignas(16) ushort T[64][66];  // [kp_local][n_local], padded
  const float* src = blockIdx.z ? F : E;
  ushort* dst = blockIdx.z ? Ft : Et;
  const int n0 = blockIdx.x * 64, kp0 = blockIdx.y * 64;
  const int t = threadIdx.x;
  {
    const int n = t >> 2, c16 = (t & 3) * 16;
    const size_t gbase = (size_t)(n0 + n) * KP_ + kp0 + c16;
#pragma unroll
    for (int q = 0; q < 4; ++q) {
      float4 x = *reinterpret_cast<const float4*>(src + gbase + q * 4);
      T[c16 + q * 4 + 0][n] = f2bf(x.x);
      T[c16 + q * 4 + 1][n] = f2bf(x.y);
      T[c16 + q * 4 + 2][n] = f2bf(x.z);
      T[c16 + q * 4 + 3][n] = f2bf(x.w);
    }
  }
  __syncthreads();
  {
    const int kp = t >> 2, n16 = (t & 3) * 16;
    BF8 x0, x1;
#pragma unroll
    for (int i = 0; i < 8; ++i) { x0.us[i] = T[kp][n16 + i]; x1.us[i] = T[kp][n16 + 8 + i]; }
    const size_t ob = (size_t)(kp0 + kp) * N_ + n0 + n16;
    *reinterpret_cast<uint4*>(dst + ob) = x0.u4;
    *reinterpret_cast<uint4*>(dst + ob + 8) = x1.u4;
  }
}

// ---------------------------------------------------------------------------
// Kernel: Kp[bh][kp][e] (bf16 hi+lo) and Vpt[bh][e][kp] from prepped
// transposes. Grid (KP/64, BH), block 256; wave w owns kp tile [w*16,+16).
// Barrier-free: all fragments are contiguous global uint4 loads.
// ---------------------------------------------------------------------------
__global__ __launch_bounds__(256) void k_linproj(const ushort* __restrict__ Et,
                                                 const ushort* __restrict__ Ft,
                                                 const ushort* __restrict__ Kt,
                                                 const ushort* __restrict__ Vt,
                                                 ushort* __restrict__ KpHi,
                                                 ushort* __restrict__ KpLo,
                                                 ushort* __restrict__ Vpt) {
  const int bh = blockIdx.y;
  const int t = threadIdx.x;
  const int w = t >> 6, lane = t & 63, quad = lane >> 4, l15 = lane & 15;
  const int kp_row = blockIdx.x * 64 + w * 16 + l15;

  const ushort* eA = Et + (size_t)kp_row * N_ + quad * 8;
  const ushort* fA = Ft + (size_t)kp_row * N_ + quad * 8;
  const ushort* kB0 = Kt + ((size_t)bh * D_ + l15) * N_ + quad * 8;
  const ushort* kB1 = kB0 + (size_t)16 * N_;
  const ushort* vB0 = Vt + ((size_t)bh * D_ + l15) * N_ + quad * 8;
  const ushort* vB1 = vB0 + (size_t)16 * N_;

  f32x4 accK0 = {0.f,0.f,0.f,0.f}, accK1 = {0.f,0.f,0.f,0.f};
  f32x4 accV0 = {0.f,0.f,0.f,0.f}, accV1 = {0.f,0.f,0.f,0.f};

  for (int n0 = 0; n0 < N_; n0 += 32) {
    BF8 aE, aF, b0, b1, b2, b3;
    aE.u4 = *reinterpret_cast<const uint4*>(eA + n0);
    aF.u4 = *reinterpret_cast<const uint4*>(fA + n0);
    b0.u4 = *reinterpret_cast<const uint4*>(kB0 + n0);
    b1.u4 = *reinterpret_cast<const uint4*>(kB1 + n0);
    b2.u4 = *reinterpret_cast<const uint4*>(vB0 + n0);
    b3.u4 = *reinterpret_cast<const uint4*>(vB1 + n0);
    accK0 = __builtin_amdgcn_mfma_f32_16x16x32_bf16(aE.b, b0.b, accK0, 0, 0, 0);
    accK1 = __builtin_amdgcn_mfma_f32_16x16x32_bf16(aE.b, b1.b, accK1, 0, 0, 0);
    accV0 = __builtin_amdgcn_mfma_f32_16x16x32_bf16(aF.b, b2.b, accV0, 0, 0, 0);
    accV1 = __builtin_amdgcn_mfma_f32_16x16x32_bf16(aF.b, b3.b, accV1, 0, 0, 0);
  }

#pragma unroll
  for (int r = 0; r < 4; ++r) {
    const int kp = blockIdx.x * 64 + w * 16 + quad * 4 + r;
    const size_t rowb = ((size_t)bh * KP_ + kp) * D_;
    ushort h0 = f2bf(accK0[r]), h1 = f2bf(accK1[r]);
    KpHi[rowb + l15]      = h0;
    KpHi[rowb + 16 + l15] = h1;
    KpLo[rowb + l15]      = f2bf_lo(accK0[r], h0);
    KpLo[rowb + 16 + l15] = f2bf_lo(accK1[r], h1);
    Vpt[((size_t)bh * D_ + l15) * KP_ + kp]      = f2bf(accV0[r]);
    Vpt[((size_t)bh * D_ + 16 + l15) * KP_ + kp] = f2bf(accV1[r]);
  }
}

// ---------------------------------------------------------------------------
// Kernel: causal full attention, fully wave-independent (no __syncthreads).
// Grid (N/64, BH), block 256; wave w owns q rows [bx*64+w*16, +16).
// Fast path: all chunks except the last are fully unmasked.
// ---------------------------------------------------------------------------
__global__ __launch_bounds__(256) void k_attn_full(const float* __restrict__ Q,
                                                   const ushort* __restrict__ KH,
                                                   const ushort* __restrict__ KL,
                                                   const ushort* __restrict__ Vt,
                                                   float* __restrict__ out) {
  __shared__ alignas(16) ushort P[4][16][34];  // per-wave P tile, padded rows
  const int bh = blockIdx.y, b = bh >> 3, h = bh & 7;
  const int t = threadIdx.x;
  const int w = t >> 6, lane = t & 63;
  const int quad = lane >> 4, l15 = lane & 15;
  const int q0 = blockIdx.x * 64 + w * 16;

  BF8 aqh, aql;
  load8_split(Q + ((size_t)(b * N_ + q0 + l15) * H_ + h) * D_ + quad * 8, aqh, aql);

  const ushort* KHb = KH + (size_t)bh * N_ * D_ + quad * 8;
  const ushort* KLb = KL + (size_t)bh * N_ * D_ + quad * 8;
  const ushort* Vt0 = Vt + ((size_t)bh * D_ + l15) * N_ + quad * 8;
  const ushort* Vt1 = Vt0 + (size_t)16 * N_;

  f32x4 O0 = {0.f,0.f,0.f,0.f}, O1 = {0.f,0.f,0.f,0.f};
  float m[4], l[4];
#pragma unroll
  for (int r = 0; r < 4; ++r) { m[r] = -1e30f; l[r] = 0.f; }
  const f32x4 z = {0.f,0.f,0.f,0.f};

  const int c_last = ((q0 + 15) >> 5) << 5;  // the single partially-masked chunk

  for (int c0 = 0; c0 < c_last; c0 += 32) {  // fully unmasked chunks
    BF8 bh0, bl0, bh1, bl1;
    bh0.u4 = *reinterpret_cast<const uint4*>(KHb + (size_t)(c0 + l15) * D_);
    bh1.u4 = *reinterpret_cast<const uint4*>(KHb + (size_t)(c0 + 16 + l15) * D_);
    bl0.u4 = *reinterpret_cast<const uint4*>(KLb + (size_t)(c0 + l15) * D_);
    bl1.u4 = *reinterpret_cast<const uint4*>(KLb + (size_t)(c0 + 16 + l15) * D_);
    f32x4 s0 = __builtin_amdgcn_mfma_f32_16x16x32_bf16(aqh.b, bh0.b, z, 0, 0, 0);
    s0 = __builtin_amdgcn_mfma_f32_16x16x32_bf16(aqh.b, bl0.b, s0, 0, 0, 0);
    s0 = __builtin_amdgcn_mfma_f32_16x16x32_bf16(aql.b, bh0.b, s0, 0, 0, 0);
    f32x4 s1 = __builtin_amdgcn_mfma_f32_16x16x32_bf16(aqh.b, bh1.b, z, 0, 0, 0);
    s1 = __builtin_amdgcn_mfma_f32_16x16x32_bf16(aqh.b, bl1.b, s1, 0, 0, 0);
    s1 = __builtin_amdgcn_mfma_f32_16x16x32_bf16(aql.b, bh1.b, s1, 0, 0, 0);

#pragma unroll
    for (int r = 0; r < 4; ++r) {
      const float v0 = s0[r] * SCALE, v1 = s1[r] * SCALE;
      const float cm = rmax16(fmaxf(v0, v1));
      const float mn = fmaxf(m[r], cm);
      const float alpha = __expf(m[r] - mn);   // first iter: exp(-huge)=0
      const float e0 = __expf(v0 - mn), e1 = __expf(v1 - mn);
      l[r] = l[r] * alpha + rsum16(e0 + e1);
      m[r] = mn;
      O0[r] *= alpha; O1[r] *= alpha;
      P[w][quad * 4 + r][l15]      = f2bf(e0);
      P[w][quad * 4 + r][16 + l15] = f2bf(e1);
    }
    lds_fence_wave();
    BF8 ap, bv0, bv1;
    ap.u4  = *reinterpret_cast<const uint4*>(&P[w][l15][quad * 8]);
    bv0.u4 = *reinterpret_cast<const uint4*>(Vt0 + c0);
    bv1.u4 = *reinterpret_cast<const uint4*>(Vt1 + c0);
    O0 = __builtin_amdgcn_mfma_f32_16x16x32_bf16(ap.b, bv0.b, O0, 0, 0, 0);
    O1 = __builtin_amdgcn_mfma_f32_16x16x32_bf16(ap.b, bv1.b, O1, 0, 0, 0);
  }

  {  // the single masked chunk at c_last
    const int c0 = c_last;
    BF8 bh0, bl0, bh1, bl1;
    bh0.u4 = *reinterpret_cast<const uint4*>(KHb + (size_t)(c0 + l15) * D_);
    bh1.u4 = *reinterpret_cast<const uint4*>(KHb + (size_t)(c0 + 16 + l15) * D_);
    bl0.u4 = *reinterpret_cast<const uint4*>(KLb + (size_t)(c0 + l15) * D_);
    bl1.u4 = *reinterpret_cast<const uint4*>(KLb + (size_t)(c0 + 16 + l15) * D_);
    f32x4 s0 = __builtin_amdgcn_mfma_f32_16x16x32_bf16(aqh.b, bh0.b, z, 0, 0, 0);
    s0 = __builtin_amdgcn_mfma_f32_16x16x32_bf16(aqh.b, bl0.b, s0, 0, 0, 0);
    s0 = __builtin_amdgcn_mfma_f32_16x16x32_bf16(aql.b, bh0.b, s0, 0, 0, 0);
    f32x4 s1 = __builtin_amdgcn_mfma_f32_16x16x32_bf16(aqh.b, bh1.b, z, 0, 0, 0);
    s1 = __builtin_amdgcn_mfma_f32_16x16x32_bf16(aqh.b, bl1.b, s1, 0, 0, 0);
    s1 = __builtin_amdgcn_mfma_f32_16x16x32_bf16(aql.b, bh1.b, s1, 0, 0, 0);

#pragma unroll
    for (int r = 0; r < 4; ++r) {
      const int qrow = q0 + quad * 4 + r;
      const bool ok0 = (c0 + l15      <= qrow);
      const bool ok1 = (c0 + 16 + l15 <= qrow);
      const float v0 = s0[r] * SCALE, v1 = s1[r] * SCALE;
      const float x0 = ok0 ? v0 : -1e30f;
      const float x1 = ok1 ? v1 : -1e30f;
      const float cm = rmax16(fmaxf(x0, x1));  // each row has >=1 valid key
      const float mn = fmaxf(m[r], cm);
      const float alpha = __expf(m[r] - mn);
      const float e0 = ok0 ? __expf(v0 - mn) : 0.f;
      const float e1 = ok1 ? __expf(v1 - mn) : 0.f;
      l[r] = l[r] * alpha + rsum16(e0 + e1);
      m[r] = mn;
      O0[r] *= alpha; O1[r] *= alpha;
      P[w][quad * 4 + r][l15]      = f2bf(e0);
      P[w][quad * 4 + r][16 + l15] = f2bf(e1);
    }
    lds_fence_wave();
    BF8 ap, bv0, bv1;
    ap.u4  = *reinterpret_cast<const uint4*>(&P[w][l15][quad * 8]);
    bv0.u4 = *reinterpret_cast<const uint4*>(Vt0 + c0);
    bv1.u4 = *reinterpret_cast<const uint4*>(Vt1 + c0);
    O0 = __builtin_amdgcn_mfma_f32_16x16x32_bf16(ap.b, bv0.b, O0, 0, 0, 0);
    O1 = __builtin_amdgcn_mfma_f32_16x16x32_bf16(ap.b, bv1.b, O1, 0, 0, 0);
  }

#pragma unroll
  for (int r = 0; r < 4; ++r) {
    const float inv = 1.f / l[r];
    const int qrow = q0 + quad * 4 + r;
    const size_t base = ((size_t)(b * N_ + qrow) * H_ + h) * D_;
    out[base + l15]      = O0[r] * inv;
    out[base + 16 + l15] = O1[r] * inv;
  }
}

// ---------------------------------------------------------------------------
// Kernel: Linformer attention: s = Q*Kp^T*scale, softmax over 256, *Vp.
// Grid (N/64, BH), block 256; wave-independent (P per wave, wave fence only).
// ---------------------------------------------------------------------------
__global__ __launch_bounds__(256) void k_attn_lin(const float* __restrict__ Q,
                                                  const ushort* __restrict__ KpHi,
                                                  const ushort* __restrict__ KpLo,
                                                  const ushort* __restrict__ Vpt,
                                                  float* __restrict__ out) {
  __shared__ alignas(16) ushort P[4][16][268];  // padded rows (268 ushorts)
  const int bh = blockIdx.y, b = bh >> 3, h = bh & 7;
  const int w = threadIdx.x >> 6, lane = threadIdx.x & 63;
  const int quad = lane >> 4, l15 = lane & 15;
  const int q0 = blockIdx.x * 64 + w * 16;

  BF8 aqh, aql;
  load8_split(Q + ((size_t)(b * N_ + q0 + l15) * H_ + h) * D_ + quad * 8, aqh, aql);

  const f32x4 z = {0.f,0.f,0.f,0.f};
  f32x4 s[16];
#pragma unroll
  for (int kt = 0; kt < 16; ++kt) {
    BF8 bkh, bkl;
    const size_t rb = ((size_t)bh * KP_ + kt * 16 + l15) * D_ + quad * 8;
    bkh.u4 = *reinterpret_cast<const uint4*>(KpHi + rb);
    bkl.u4 = *reinterpret_cast<const uint4*>(KpLo + rb);
    s[kt] = __builtin_amdgcn_mfma_f32_16x16x32_bf16(aqh.b, bkh.b, z, 0, 0, 0);
    s[kt] = __builtin_amdgcn_mfma_f32_16x16x32_bf16(aqh.b, bkl.b, s[kt], 0, 0, 0);
    s[kt] = __builtin_amdgcn_mfma_f32_16x16x32_bf16(aql.b, bkh.b, s[kt], 0, 0, 0);
  }

  float l[4];
#pragma unroll
  for (int r = 0; r < 4; ++r) {
    float mm = -1e30f;
#pragma unroll
    for (int kt = 0; kt < 16; ++kt) mm = fmaxf(mm, s[kt][r]);
    mm = rmax16(mm * SCALE);
    float sum = 0.f;
#pragma unroll
    for (int kt = 0; kt < 16; ++kt) {
      const float e = __expf(s[kt][r] * SCALE - mm);
      sum += e;
      P[w][quad * 4 + r][kt * 16 + l15] = f2bf(e);
    }
    l[r] = rsum16(sum);
  }
  lds_fence_wave();

  f32x4 O0 = {0.f,0.f,0.f,0.f}, O1 = {0.f,0.f,0.f,0.f};
#pragma unroll
  for (int c = 0; c < 8; ++c) {
    BF8 ap, bv0, bv1;
    ap.u4 = *reinterpret_cast<const uint4*>(&P[w][l15][c * 32 + quad * 8]);
    bv0.u4 = *reinterpret_cast<const uint4*>(
        Vpt + ((size_t)bh * D_ + l15) * KP_ + c * 32 + quad * 8);
    bv1.u4 = *reinterpret_cast<const uint4*>(
        Vpt + ((size_t)bh * D_ + 16 + l15) * KP_ + c * 32 + quad * 8);
    O0 = __builtin_amdgcn_mfma_f32_16x16x32_bf16(ap.b, bv0.b, O0, 0, 0, 0);
    O1 = __builtin_amdgcn_mfma_f32_16x16x32_bf16(ap.b, bv1.b, O1, 0, 0, 0);
  }

#pragma unroll
  for (int r = 0; r < 4; ++r) {
    const float inv = 1.f / l[r];
    const int qrow = q0 + quad * 4 + r;
    const size_t base = ((size_t)(b * N_ + qrow) * H_ + h) * D_;
    out[base + l15]      = O0[r] * inv;
    out[base + 16 + l15] = O1[r] * inv;
  }
}

// ---------------------------------------------------------------------------
extern "C" void kernel_launch(void* const* d_in, const int* in_sizes, int n_in,
                              void* d_out, int out_size, void* d_ws, size_t ws_size,
                              hipStream_t stream) {
  const float* Q = (const float*)d_in[0];
  const float* K = (const float*)d_in[1];
  const float* V = (const float*)d_in[2];
  const float* E = (const float*)d_in[3];
  const float* F = (const float*)d_in[4];
  float* out = (float*)d_out;

  // workspace layout (ushort elements), ~20.4 MB total
  ushort* KH  = (ushort*)d_ws;                        // [BH][N][D]  4 MB
  ushort* KL  = KH + (size_t)BH_ * N_ * D_;           // [BH][N][D]  4 MB
  ushort* Kt  = KL + (size_t)BH_ * N_ * D_;           // [BH][D][N]  4 MB
  ushort* Vt  = Kt + (size_t)BH_ * N_ * D_;           // [BH][D][N]  4 MB
  ushort* Et  = Vt + (size_t)BH_ * N_ * D_;           // [KP][N]     1 MB
  ushort* Ft  = Et + (size_t)KP_ * N_;                // [KP][N]     1 MB
  ushort* KpHi = Ft + (size_t)KP_ * N_;               // [BH][KP][D] 0.5 MB
  ushort* KpLo = KpHi + (size_t)BH_ * KP_ * D_;       // [BH][KP][D] 0.5 MB
  ushort* Vpt  = KpLo + (size_t)BH_ * KP_ * D_;       // [BH][D][KP] 0.5 MB

  k_prep_kv<<<dim3(N_ / 64, BH_), 256, 0, stream>>>(K, V, KH, KL, Kt, Vt);
  k_prep_ef<<<dim3(N_ / 64, KP_ / 64, 2), 256, 0, stream>>>(E, F, Et, Ft);
  k_linproj<<<dim3(KP_ / 64, BH_), 256, 0, stream>>>(Et, Ft, Kt, Vt,
                                                     KpHi, KpLo, Vpt);
  k_attn_full<<<dim3(N_ / 64, BH_), 256, 0, stream>>>(Q, KH, KL, Vt, out);
  k_attn_lin<<<dim3(N_ / 64, BH_), 256, 0, stream>>>(
      Q, KpHi, KpLo, Vpt, out + (size_t)B_ * N_ * H_ * D_);
}

// Round 6
// 265.734 us; speedup vs baseline: 1.3933x; 1.0393x over previous
//
#include <hip/hip_runtime.h>
#include <hip/hip_bf16.h>

// dsfa_former: (1) causal full attention + (2) Linformer attention.
// Inputs fp32, outputs fp32. Internal compute bf16 MFMA (split-bf16 scores).
// B=4, N=2048, H=8, d=32, kproj=256.
//
// Round-6: S^T trick. Scores computed as S^T = K·Q^T with a permuted K-row
// assignment (lane m loads key 8*(m>>2)+(m&3)), so the two 16-key S^T
// accumulators sit exactly in the A-operand layout of the P·V MFMA:
//   S^T C-layout: lane(quad,l15) reg r = S[q=l15][key = 8*quad + r (+4)]
//   PV  A-layout: lane(quad,l15) needs P[q=l15][key = quad*8 + j]   -> match.
// exp() is applied in-register, packed to bf16, fed straight to PV MFMA.
// No LDS, no fences, 8 shuffles per 32-key chunk (was 32 + LDS round-trip).
//
// Fragment layouts (learn_hip m89/m91/m120):
//   C/D: per-lane row = quad*4 + reg, col = lane&15
//   A:   lane holds A[m = lane&15][k = quad*8 + j], j=0..7
//   B:   lane holds B[k = quad*8 + j][n = lane&15]
// Note Q[q][e] per-lane (q=l15, e=quad*8+j) serves as BOTH A(m=q,k=e) and
// B(k=e,n=q) — so Q^T's B-frag is the same registers as Q's A-frag.

typedef __bf16 bf16x8 __attribute__((ext_vector_type(8)));
typedef float f32x4 __attribute__((ext_vector_type(4)));

union BF8 { uint4 u4; ushort us[8]; bf16x8 b; };

constexpr int B_ = 4, N_ = 2048, H_ = 8, D_ = 32, KP_ = 256, BH_ = 32;
constexpr float SCALE = 0.17677669529663687f;  // 1/sqrt(32)

__device__ __forceinline__ ushort f2bf(float f) {
  unsigned u = __builtin_bit_cast(unsigned, f);
  return (ushort)((u + 0x7FFFu + ((u >> 16) & 1u)) >> 16);
}
__device__ __forceinline__ float bf2f(ushort h) {
  return __builtin_bit_cast(float, (unsigned)h << 16);
}
__device__ __forceinline__ ushort f2bf_lo(float f, ushort hi) {
  return f2bf(f - bf2f(hi));
}

// Load 8 consecutive floats (scaled), return hi/lo bf16 fragments.
__device__ __forceinline__ void load8_split_scaled(const float* __restrict__ p,
                                                   float scale, BF8& hi, BF8& lo) {
  float4 a = *reinterpret_cast<const float4*>(p);
  float4 b = *reinterpret_cast<const float4*>(p + 4);
  float x[8] = {a.x, a.y, a.z, a.w, b.x, b.y, b.z, b.w};
#pragma unroll
  for (int i = 0; i < 8; ++i) {
    const float v = x[i] * scale;
    hi.us[i] = f2bf(v);
    lo.us[i] = f2bf_lo(v, hi.us[i]);
  }
}
__device__ __forceinline__ void load8_split(const float* __restrict__ p,
                                            BF8& hi, BF8& lo) {
  load8_split_scaled(p, 1.0f, hi, lo);
}

// ---------------------------------------------------------------------------
// Prep 1: K -> KH/KL[bh][n][e] (split bf16, row-major), K -> Kt[bh][e][n],
//         V -> Vt[bh][e][n]. Grid (N/64, BH), block 256. One-shot.
// ---------------------------------------------------------------------------
__global__ __launch_bounds__(256) void k_prep_kv(const float* __restrict__ K,
                                                 const float* __restrict__ V,
                                                 ushort* __restrict__ KH,
                                                 ushort* __restrict__ KL,
                                                 ushort* __restrict__ Kt,
                                                 ushort* __restrict__ Vt) {
  __shared__ alignas(16) ushort Tk[D_][66];  // [e][n_local], padded
  __shared__ alignas(16) ushort Tv[D_][66];
  const int bh = blockIdx.y, b = bh >> 3, h = bh & 7;
  const int n0 = blockIdx.x * 64;
  const int t = threadIdx.x;
  {
    const int row = t >> 2, e8 = (t & 3) * 8;
    const size_t gbase = ((size_t)(b * N_ + n0 + row) * H_ + h) * D_ + e8;
    float4 k0 = *reinterpret_cast<const float4*>(K + gbase);
    float4 k1 = *reinterpret_cast<const float4*>(K + gbase + 4);
    float4 v0 = *reinterpret_cast<const float4*>(V + gbase);
    float4 v1 = *reinterpret_cast<const float4*>(V + gbase + 4);
    float kk[8] = {k0.x,k0.y,k0.z,k0.w,k1.x,k1.y,k1.z,k1.w};
    float vv[8] = {v0.x,v0.y,v0.z,v0.w,v1.x,v1.y,v1.z,v1.w};
    BF8 xh, xl;
#pragma unroll
    for (int i = 0; i < 8; ++i) {
      xh.us[i] = f2bf(kk[i]);
      xl.us[i] = f2bf_lo(kk[i], xh.us[i]);
      Tk[e8 + i][row] = xh.us[i];
      Tv[e8 + i][row] = f2bf(vv[i]);
    }
    const size_t ob = ((size_t)bh * N_ + n0 + row) * D_ + e8;
    *reinterpret_cast<uint4*>(KH + ob) = xh.u4;
    *reinterpret_cast<uint4*>(KL + ob) = xl.u4;
  }
  __syncthreads();
  {
    const int e = t >> 3, n8 = (t & 7) * 8;
    BF8 xk, xv;
#pragma unroll
    for (int i = 0; i < 8; ++i) { xk.us[i] = Tk[e][n8 + i]; xv.us[i] = Tv[e][n8 + i]; }
    const size_t ob = ((size_t)bh * D_ + e) * N_ + n0 + n8;
    *reinterpret_cast<uint4*>(Kt + ob) = xk.u4;
    *reinterpret_cast<uint4*>(Vt + ob) = xv.u4;
  }
}

// ---------------------------------------------------------------------------
// Prep 2: E[N][KP] -> Et[KP][N] bf16 (z=0), F -> Ft (z=1).
// Grid (N/64, KP/64, 2), block 256. One-shot.
// ---------------------------------------------------------------------------
__global__ __launch_bounds__(256) void k_prep_ef(const float* __restrict__ E,
                                                 const float* __restrict__ F,
                                                 ushort* __restrict__ Et,
                                                 ushort* __restrict__ Ft) {
  __shared__ alignas(16) ushort T[64][66];  // [kp_local][n_local], padded
  const float* src = blockIdx.z ? F : E;
  ushort* dst = blockIdx.z ? Ft : Et;
  const int n0 = blockIdx.x * 64, kp0 = blockIdx.y * 64;
  const int t = threadIdx.x;
  {
    const int n = t >> 2, c16 = (t & 3) * 16;
    const size_t gbase = (size_t)(n0 + n) * KP_ + kp0 + c16;
#pragma unroll
    for (int q = 0; q < 4; ++q) {
      float4 x = *reinterpret_cast<const float4*>(src + gbase + q * 4);
      T[c16 + q * 4 + 0][n] = f2bf(x.x);
      T[c16 + q * 4 + 1][n] = f2bf(x.y);
      T[c16 + q * 4 + 2][n] = f2bf(x.z);
      T[c16 + q * 4 + 3][n] = f2bf(x.w);
    }
  }
  __syncthreads();
  {
    const int kp = t >> 2, n16 = (t & 3) * 16;
    BF8 x0, x1;
#pragma unroll
    for (int i = 0; i < 8; ++i) { x0.us[i] = T[kp][n16 + i]; x1.us[i] = T[kp][n16 + 8 + i]; }
    const size_t ob = (size_t)(kp0 + kp) * N_ + n0 + n16;
    *reinterpret_cast<uint4*>(dst + ob) = x0.u4;
    *reinterpret_cast<uint4*>(dst + ob + 8) = x1.u4;
  }
}

// ---------------------------------------------------------------------------
// Kernel: Kp[bh][kp][e] (bf16 hi+lo) and Vpt[bh][e][kp] from prepped
// transposes. Grid (KP/64, BH), block 256; wave w owns kp tile [w*16,+16).
// Barrier-free: all fragments are contiguous global uint4 loads.
// ---------------------------------------------------------------------------
__global__ __launch_bounds__(256) void k_linproj(const ushort* __restrict__ Et,
                                                 const ushort* __restrict__ Ft,
                                                 const ushort* __restrict__ Kt,
                                                 const ushort* __restrict__ Vt,
                                                 ushort* __restrict__ KpHi,
                                                 ushort* __restrict__ KpLo,
                                                 ushort* __restrict__ Vpt) {
  const int bh = blockIdx.y;
  const int t = threadIdx.x;
  const int w = t >> 6, lane = t & 63, quad = lane >> 4, l15 = lane & 15;
  const int kp_row = blockIdx.x * 64 + w * 16 + l15;

  const ushort* eA = Et + (size_t)kp_row * N_ + quad * 8;
  const ushort* fA = Ft + (size_t)kp_row * N_ + quad * 8;
  const ushort* kB0 = Kt + ((size_t)bh * D_ + l15) * N_ + quad * 8;
  const ushort* kB1 = kB0 + (size_t)16 * N_;
  const ushort* vB0 = Vt + ((size_t)bh * D_ + l15) * N_ + quad * 8;
  const ushort* vB1 = vB0 + (size_t)16 * N_;

  f32x4 accK0 = {0.f,0.f,0.f,0.f}, accK1 = {0.f,0.f,0.f,0.f};
  f32x4 accV0 = {0.f,0.f,0.f,0.f}, accV1 = {0.f,0.f,0.f,0.f};

  for (int n0 = 0; n0 < N_; n0 += 32) {
    BF8 aE, aF, b0, b1, b2, b3;
    aE.u4 = *reinterpret_cast<const uint4*>(eA + n0);
    aF.u4 = *reinterpret_cast<const uint4*>(fA + n0);
    b0.u4 = *reinterpret_cast<const uint4*>(kB0 + n0);
    b1.u4 = *reinterpret_cast<const uint4*>(kB1 + n0);
    b2.u4 = *reinterpret_cast<const uint4*>(vB0 + n0);
    b3.u4 = *reinterpret_cast<const uint4*>(vB1 + n0);
    accK0 = __builtin_amdgcn_mfma_f32_16x16x32_bf16(aE.b, b0.b, accK0, 0, 0, 0);
    accK1 = __builtin_amdgcn_mfma_f32_16x16x32_bf16(aE.b, b1.b, accK1, 0, 0, 0);
    accV0 = __builtin_amdgcn_mfma_f32_16x16x32_bf16(aF.b, b2.b, accV0, 0, 0, 0);
    accV1 = __builtin_amdgcn_mfma_f32_16x16x32_bf16(aF.b, b3.b, accV1, 0, 0, 0);
  }

#pragma unroll
  for (int r = 0; r < 4; ++r) {
    const int kp = blockIdx.x * 64 + w * 16 + quad * 4 + r;
    const size_t rowb = ((size_t)bh * KP_ + kp) * D_;
    ushort h0 = f2bf(accK0[r]), h1 = f2bf(accK1[r]);
    KpHi[rowb + l15]      = h0;
    KpHi[rowb + 16 + l15] = h1;
    KpLo[rowb + l15]      = f2bf_lo(accK0[r], h0);
    KpLo[rowb + 16 + l15] = f2bf_lo(accK1[r], h1);
    Vpt[((size_t)bh * D_ + l15) * KP_ + kp]      = f2bf(accV0[r]);
    Vpt[((size_t)bh * D_ + 16 + l15) * KP_ + kp] = f2bf(accV1[r]);
  }
}

// ---------------------------------------------------------------------------
// Kernel: causal full attention, S^T trick, no LDS, no fences.
// Grid (N/64, BH), block 256; wave w owns q rows [bx*64+w*16, +16).
// Each lane's softmax row is q = q0 + l15 (replicated across 4 quads).
// ---------------------------------------------------------------------------
__global__ __launch_bounds__(256) void k_attn_full(const float* __restrict__ Q,
                                                   const ushort* __restrict__ KH,
                                                   const ushort* __restrict__ KL,
                                                   const ushort* __restrict__ Vt,
                                                   float* __restrict__ out) {
  const int bh = blockIdx.y, b = bh >> 3, h = bh & 7;
  const int t = threadIdx.x;
  const int w = t >> 6, lane = t & 63;
  const int quad = lane >> 4, l15 = lane & 15;
  const int q0 = blockIdx.x * 64 + w * 16;
  const int qrow = q0 + l15;

  BF8 qhf, qlf;  // Q pre-scaled by SCALE; serves as B-operand of S^T
  load8_split_scaled(Q + ((size_t)(b * N_ + q0 + l15) * H_ + h) * D_ + quad * 8,
                     SCALE, qhf, qlf);

  // permuted key-row assignment so S^T accs == PV A-frag layout
  const int kperm1 = 8 * (l15 >> 2) + (l15 & 3);
  const int kperm2 = kperm1 + 4;
  const ushort* KHb = KH + (size_t)bh * N_ * D_ + quad * 8;
  const ushort* KLb = KL + (size_t)bh * N_ * D_ + quad * 8;
  const ushort* Vt0 = Vt + ((size_t)bh * D_ + l15) * N_ + quad * 8;
  const ushort* Vt1 = Vt0 + (size_t)16 * N_;

  f32x4 O0 = {0.f,0.f,0.f,0.f}, O1 = {0.f,0.f,0.f,0.f};
  float m_run = -1e30f, l_run = 0.f;
  const f32x4 z = {0.f,0.f,0.f,0.f};
  const int c_last = ((q0 + 15) >> 5) << 5;  // single partially-masked chunk

  for (int c0 = 0; c0 < c_last; c0 += 32) {  // fully unmasked chunks
    BF8 a1h, a2h, a1l, a2l;
    a1h.u4 = *reinterpret_cast<const uint4*>(KHb + (size_t)(c0 + kperm1) * D_);
    a2h.u4 = *reinterpret_cast<const uint4*>(KHb + (size_t)(c0 + kperm2) * D_);
    a1l.u4 = *reinterpret_cast<const uint4*>(KLb + (size_t)(c0 + kperm1) * D_);
    a2l.u4 = *reinterpret_cast<const uint4*>(KLb + (size_t)(c0 + kperm2) * D_);
    f32x4 s1 = __builtin_amdgcn_mfma_f32_16x16x32_bf16(a1h.b, qhf.b, z, 0, 0, 0);
    s1 = __builtin_amdgcn_mfma_f32_16x16x32_bf16(a1l.b, qhf.b, s1, 0, 0, 0);
    s1 = __builtin_amdgcn_mfma_f32_16x16x32_bf16(a1h.b, qlf.b, s1, 0, 0, 0);
    f32x4 s2 = __builtin_amdgcn_mfma_f32_16x16x32_bf16(a2h.b, qhf.b, z, 0, 0, 0);
    s2 = __builtin_amdgcn_mfma_f32_16x16x32_bf16(a2l.b, qhf.b, s2, 0, 0, 0);
    s2 = __builtin_amdgcn_mfma_f32_16x16x32_bf16(a2h.b, qlf.b, s2, 0, 0, 0);
    // lane holds S[q=l15][key = c0 + 8*quad + j], j=0..3 in s1, 4..7 in s2

    float mx = fmaxf(fmaxf(fmaxf(s1[0], s1[1]), fmaxf(s1[2], s1[3])),
                     fmaxf(fmaxf(s2[0], s2[1]), fmaxf(s2[2], s2[3])));
    mx = fmaxf(mx, __shfl_xor(mx, 16));
    mx = fmaxf(mx, __shfl_xor(mx, 32));
    const float mn = fmaxf(m_run, mx);
    const float alpha = __expf(m_run - mn);
    float e[8], sum = 0.f;
#pragma unroll
    for (int r = 0; r < 4; ++r) {
      e[r]     = __expf(s1[r] - mn);
      e[4 + r] = __expf(s2[r] - mn);
      sum += e[r] + e[4 + r];
    }
    sum += __shfl_xor(sum, 16);
    sum += __shfl_xor(sum, 32);
    l_run = l_run * alpha + sum;
    m_run = mn;

    BF8 p;
#pragma unroll
    for (int j = 0; j < 8; ++j) p.us[j] = f2bf(e[j]);
    BF8 v0, v1;
    v0.u4 = *reinterpret_cast<const uint4*>(Vt0 + c0);
    v1.u4 = *reinterpret_cast<const uint4*>(Vt1 + c0);
#pragma unroll
    for (int r = 0; r < 4; ++r) {
      const float ar = __shfl(alpha, quad * 4 + r, 16);
      O0[r] *= ar; O1[r] *= ar;
    }
    O0 = __builtin_amdgcn_mfma_f32_16x16x32_bf16(p.b, v0.b, O0, 0, 0, 0);
    O1 = __builtin_amdgcn_mfma_f32_16x16x32_bf16(p.b, v1.b, O1, 0, 0, 0);
  }

  {  // the single masked chunk at c_last
    const int c0 = c_last;
    BF8 a1h, a2h, a1l, a2l;
    a1h.u4 = *reinterpret_cast<const uint4*>(KHb + (size_t)(c0 + kperm1) * D_);
    a2h.u4 = *reinterpret_cast<const uint4*>(KHb + (size_t)(c0 + kperm2) * D_);
    a1l.u4 = *reinterpret_cast<const uint4*>(KLb + (size_t)(c0 + kperm1) * D_);
    a2l.u4 = *reinterpret_cast<const uint4*>(KLb + (size_t)(c0 + kperm2) * D_);
    f32x4 s1 = __builtin_amdgcn_mfma_f32_16x16x32_bf16(a1h.b, qhf.b, z, 0, 0, 0);
    s1 = __builtin_amdgcn_mfma_f32_16x16x32_bf16(a1l.b, qhf.b, s1, 0, 0, 0);
    s1 = __builtin_amdgcn_mfma_f32_16x16x32_bf16(a1h.b, qlf.b, s1, 0, 0, 0);
    f32x4 s2 = __builtin_amdgcn_mfma_f32_16x16x32_bf16(a2h.b, qhf.b, z, 0, 0, 0);
    s2 = __builtin_amdgcn_mfma_f32_16x16x32_bf16(a2l.b, qhf.b, s2, 0, 0, 0);
    s2 = __builtin_amdgcn_mfma_f32_16x16x32_bf16(a2h.b, qlf.b, s2, 0, 0, 0);

    bool ok[8];
    float xv[8];
#pragma unroll
    for (int j = 0; j < 8; ++j) {
      const int key = c0 + 8 * quad + j;
      ok[j] = (key <= qrow);
      xv[j] = ok[j] ? (j < 4 ? s1[j] : s2[j - 4]) : -1e30f;
    }
    float mx = fmaxf(fmaxf(fmaxf(xv[0], xv[1]), fmaxf(xv[2], xv[3])),
                     fmaxf(fmaxf(xv[4], xv[5]), fmaxf(xv[6], xv[7])));
    mx = fmaxf(mx, __shfl_xor(mx, 16));
    mx = fmaxf(mx, __shfl_xor(mx, 32));
    const float mn = fmaxf(m_run, mx);  // finite: each q-row has >=1 valid key
    const float alpha = __expf(m_run - mn);
    float e[8], sum = 0.f;
#pragma unroll
    for (int j = 0; j < 8; ++j) {
      e[j] = ok[j] ? __expf((j < 4 ? s1[j] : s2[j - 4]) - mn) : 0.f;
      sum += e[j];
    }
    sum += __shfl_xor(sum, 16);
    sum += __shfl_xor(sum, 32);
    l_run = l_run * alpha + sum;

    BF8 p;
#pragma unroll
    for (int j = 0; j < 8; ++j) p.us[j] = f2bf(e[j]);
    BF8 v0, v1;
    v0.u4 = *reinterpret_cast<const uint4*>(Vt0 + c0);
    v1.u4 = *reinterpret_cast<const uint4*>(Vt1 + c0);
#pragma unroll
    for (int r = 0; r < 4; ++r) {
      const float ar = __shfl(alpha, quad * 4 + r, 16);
      O0[r] *= ar; O1[r] *= ar;
    }
    O0 = __builtin_amdgcn_mfma_f32_16x16x32_bf16(p.b, v0.b, O0, 0, 0, 0);
    O1 = __builtin_amdgcn_mfma_f32_16x16x32_bf16(p.b, v1.b, O1, 0, 0, 0);
  }

  const float inv = 1.f / l_run;
#pragma unroll
  for (int r = 0; r < 4; ++r) {
    const float fr = __shfl(inv, quad * 4 + r, 16);
    const int q = q0 + quad * 4 + r;
    const size_t base = ((size_t)(b * N_ + q) * H_ + h) * D_;
    out[base + l15]      = O0[r] * fr;
    out[base + 16 + l15] = O1[r] * fr;
  }
}

// ---------------------------------------------------------------------------
// Kernel: Linformer attention, S^T trick, no LDS.
// Grid (N/64, BH), block 256; wave w owns q rows [bx*64+w*16, +16).
// ---------------------------------------------------------------------------
__global__ __launch_bounds__(256) void k_attn_lin(const float* __restrict__ Q,
                                                  const ushort* __restrict__ KpHi,
                                                  const ushort* __restrict__ KpLo,
                                                  const ushort* __restrict__ Vpt,
                                                  float* __restrict__ out) {
  const int bh = blockIdx.y, b = bh >> 3, h = bh & 7;
  const int t = threadIdx.x;
  const int w = t >> 6, lane = t & 63;
  const int quad = lane >> 4, l15 = lane & 15;
  const int q0 = blockIdx.x * 64 + w * 16;

  BF8 qhf, qlf;
  load8_split_scaled(Q + ((size_t)(b * N_ + q0 + l15) * H_ + h) * D_ + quad * 8,
                     SCALE, qhf, qlf);

  const int kperm1 = 8 * (l15 >> 2) + (l15 & 3);
  const int kperm2 = kperm1 + 4;
  const ushort* KpHb = KpHi + (size_t)bh * KP_ * D_ + quad * 8;
  const ushort* KpLb = KpLo + (size_t)bh * KP_ * D_ + quad * 8;
  const ushort* Vp0 = Vpt + ((size_t)bh * D_ + l15) * KP_ + quad * 8;
  const ushort* Vp1 = Vp0 + (size_t)16 * KP_;

  const f32x4 z = {0.f,0.f,0.f,0.f};
  f32x4 s1[8], s2[8];
#pragma unroll
  for (int g = 0; g < 8; ++g) {
    const int kp0 = g * 32;
    BF8 a1h, a2h, a1l, a2l;
    a1h.u4 = *reinterpret_cast<const uint4*>(KpHb + (size_t)(kp0 + kperm1) * D_);
    a2h.u4 = *reinterpret_cast<const uint4*>(KpHb + (size_t)(kp0 + kperm2) * D_);
    a1l.u4 = *reinterpret_cast<const uint4*>(KpLb + (size_t)(kp0 + kperm1) * D_);
    a2l.u4 = *reinterpret_cast<const uint4*>(KpLb + (size_t)(kp0 + kperm2) * D_);
    s1[g] = __builtin_amdgcn_mfma_f32_16x16x32_bf16(a1h.b, qhf.b, z, 0, 0, 0);
    s1[g] = __builtin_amdgcn_mfma_f32_16x16x32_bf16(a1l.b, qhf.b, s1[g], 0, 0, 0);
    s1[g] = __builtin_amdgcn_mfma_f32_16x16x32_bf16(a1h.b, qlf.b, s1[g], 0, 0, 0);
    s2[g] = __builtin_amdgcn_mfma_f32_16x16x32_bf16(a2h.b, qhf.b, z, 0, 0, 0);
    s2[g] = __builtin_amdgcn_mfma_f32_16x16x32_bf16(a2l.b, qhf.b, s2[g], 0, 0, 0);
    s2[g] = __builtin_amdgcn_mfma_f32_16x16x32_bf16(a2h.b, qlf.b, s2[g], 0, 0, 0);
  }

  float mx = -1e30f;
#pragma unroll
  for (int g = 0; g < 8; ++g)
#pragma unroll
    for (int r = 0; r < 4; ++r) mx = fmaxf(mx, fmaxf(s1[g][r], s2[g][r]));
  mx = fmaxf(mx, __shfl_xor(mx, 16));
  mx = fmaxf(mx, __shfl_xor(mx, 32));

  float sum = 0.f;
#pragma unroll
  for (int g = 0; g < 8; ++g)
#pragma unroll
    for (int r = 0; r < 4; ++r) {
      s1[g][r] = __expf(s1[g][r] - mx);
      s2[g][r] = __expf(s2[g][r] - mx);
      sum += s1[g][r] + s2[g][r];
    }
  sum += __shfl_xor(sum, 16);
  sum += __shfl_xor(sum, 32);
  const float inv = 1.f / sum;  // per q=l15; folded into P below

  f32x4 O0 = {0.f,0.f,0.f,0.f}, O1 = {0.f,0.f,0.f,0.f};
#pragma unroll
  for (int g = 0; g < 8; ++g) {
    BF8 p;
#pragma unroll
    for (int r = 0; r < 4; ++r) {
      p.us[r]     = f2bf(s1[g][r] * inv);
      p.us[4 + r] = f2bf(s2[g][r] * inv);
    }
    BF8 v0, v1;
    v0.u4 = *reinterpret_cast<const uint4*>(Vp0 + g * 32);
    v1.u4 = *reinterpret_cast<const uint4*>(Vp1 + g * 32);
    O0 = __builtin_amdgcn_mfma_f32_16x16x32_bf16(p.b, v0.b, O0, 0, 0, 0);
    O1 = __builtin_amdgcn_mfma_f32_16x16x32_bf16(p.b, v1.b, O1, 0, 0, 0);
  }

#pragma unroll
  for (int r = 0; r < 4; ++r) {
    const int q = q0 + quad * 4 + r;
    const size_t base = ((size_t)(b * N_ + q) * H_ + h) * D_;
    out[base + l15]      = O0[r];
    out[base + 16 + l15] = O1[r];
  }
}

// ---------------------------------------------------------------------------
extern "C" void kernel_launch(void* const* d_in, const int* in_sizes, int n_in,
                              void* d_out, int out_size, void* d_ws, size_t ws_size,
                              hipStream_t stream) {
  const float* Q = (const float*)d_in[0];
  const float* K = (const float*)d_in[1];
  const float* V = (const float*)d_in[2];
  const float* E = (const float*)d_in[3];
  const float* F = (const float*)d_in[4];
  float* out = (float*)d_out;

  // workspace layout (ushort elements), ~20.4 MB total
  ushort* KH  = (ushort*)d_ws;                        // [BH][N][D]  4 MB
  ushort* KL  = KH + (size_t)BH_ * N_ * D_;           // [BH][N][D]  4 MB
  ushort* Kt  = KL + (size_t)BH_ * N_ * D_;           // [BH][D][N]  4 MB
  ushort* Vt  = Kt + (size_t)BH_ * N_ * D_;           // [BH][D][N]  4 MB
  ushort* Et  = Vt + (size_t)BH_ * N_ * D_;           // [KP][N]     1 MB
  ushort* Ft  = Et + (size_t)KP_ * N_;                // [KP][N]     1 MB
  ushort* KpHi = Ft + (size_t)KP_ * N_;               // [BH][KP][D] 0.5 MB
  ushort* KpLo = KpHi + (size_t)BH_ * KP_ * D_;       // [BH][KP][D] 0.5 MB
  ushort* Vpt  = KpLo + (size_t)BH_ * KP_ * D_;       // [BH][D][KP] 0.5 MB

  k_prep_kv<<<dim3(N_ / 64, BH_), 256, 0, stream>>>(K, V, KH, KL, Kt, Vt);
  k_prep_ef<<<dim3(N_ / 64, KP_ / 64, 2), 256, 0, stream>>>(E, F, Et, Ft);
  k_linproj<<<dim3(KP_ / 64, BH_), 256, 0, stream>>>(Et, Ft, Kt, Vt,
                                                     KpHi, KpLo, Vpt);
  k_attn_full<<<dim3(N_ / 64, BH_), 256, 0, stream>>>(Q, KH, KL, Vt, out);
  k_attn_lin<<<dim3(N_ / 64, BH_), 256, 0, stream>>>(
      Q, KpHi, KpLo, Vpt, out + (size_t)B_ * N_ * H_ * D_);
}